// Round 5
// baseline (508.564 us; speedup 1.0000x reference)
//
#include <hip/hip_runtime.h>
#include <math.h>

#define B_           1024
#define S_           200
#define H_           128
#define VOCAB_       100000
#define PAD_ID_      99998
#define INTEREST_ID_ 99999
#define NTHREADS_    512   // 8 waves/block; 1024 blocks -> 4 blocks/CU

// Native clang vector type: __builtin_nontemporal_* requires scalar/ext_vector
// pointers (HIP_vector_type float4 is rejected).
typedef float vfloat4 __attribute__((ext_vector_type(4)));

// One block per batch row.
//   A. zero-fill out[b,:] with NON-TEMPORAL 16B stores (streaming; no L2
//      pollution from 410 MB of single-use zeros)
//   B. score compute with NON-TEMPORAL 16B loads (hs rows are single-use)
//   C. __syncthreads (vmcnt(0) drain -> zeros globally visible)
//   D. masked softmax + atomicAdd scatter into the row this block owns.
//
// Measured context (R3): dur_us includes ~360 us of harness poison/restore
// (1.64 GB ws fill @260us + 410 MB out fill @66us + d_in restore @~35us);
// the kernel itself is ~140 us vs an ~88 us mixed-BW roofline.
__global__ __launch_bounds__(NTHREADS_) void rd90220_fused_v5(
    const float* __restrict__ hs,
    const int*   __restrict__ ids,
    const float* __restrict__ w,
    const float* __restrict__ bp,
    float*       __restrict__ out)
{
    __shared__ float s_scores[S_];
    __shared__ float s_red[16];

    const int batch = blockIdx.x;
    const int tid   = threadIdx.x;
    const int wave  = tid >> 6;
    const int lane  = tid & 63;
    const int half  = lane >> 5;   // which of the 2 rows this half-wave handles
    const int hl    = lane & 31;   // lane within half: h = hl*4 .. hl*4+3

    const float* hsb  = hs + (size_t)batch * (S_ * H_);
    float*       rowo = out + (size_t)batch * VOCAB_;

    // ---- Phase A: zero this block's output row (25000 x 16B = 400 KB),
    // streaming stores issued first so they overlap the score-phase loads.
    {
        vfloat4* rowo4 = (vfloat4*)rowo;
        const vfloat4 z = {0.f, 0.f, 0.f, 0.f};
        #pragma unroll 4
        for (int i = tid; i < VOCAB_ / 4; i += NTHREADS_)
            __builtin_nontemporal_store(z, rowo4 + i);
    }

    // Token id load (single-use, overlaps everything below).
    int   id    = 0;
    bool  valid = false;
    if (tid < S_) {
        id    = ids[batch * S_ + tid];
        valid = (id != PAD_ID_) && (id != INTEREST_ID_);
    }

    // ---- Phase B: scores. key/w are tiny + reused -> normal loads.
    const vfloat4 key = ((const vfloat4*)hsb)[hl];
    const vfloat4 wv  = ((const vfloat4*)w)[hl];

    for (int s0 = wave * 2; s0 < S_; s0 += 16) {
        const int s = s0 + half;                      // covers every s in [0,200)
        const vfloat4 x =
            __builtin_nontemporal_load(((const vfloat4*)(hsb + s * H_)) + hl);
        float acc = tanhf(x.x + key.x) * wv.x
                  + tanhf(x.y + key.y) * wv.y
                  + tanhf(x.z + key.z) * wv.z
                  + tanhf(x.w + key.w) * wv.w;
        #pragma unroll
        for (int off = 16; off; off >>= 1)            // xor masks <32 stay in-half
            acc += __shfl_xor(acc, off, 64);
        if (hl == 0) s_scores[s] = acc;
    }

    __syncthreads();   // scores visible; zero stores fully drained

    // ---- Phase D: masked softmax over 200 scores ----
    const float bias = bp[0];
    float sc = (tid < S_ && valid) ? (s_scores[tid] + bias) : -INFINITY;

    float m = sc;
    #pragma unroll
    for (int off = 32; off; off >>= 1)
        m = fmaxf(m, __shfl_down(m, off, 64));
    if (lane == 0) s_red[wave] = m;
    __syncthreads();
    m = fmaxf(fmaxf(fmaxf(s_red[0], s_red[1]), fmaxf(s_red[2], s_red[3])),
              fmaxf(fmaxf(s_red[4], s_red[5]), fmaxf(s_red[6], s_red[7])));

    const float e = (tid < S_ && valid) ? expf(sc - m) : 0.0f;
    float t = e;
    #pragma unroll
    for (int off = 32; off; off >>= 1)
        t += __shfl_down(t, off, 64);
    if (lane == 0) s_red[8 + wave] = t;
    __syncthreads();
    const float sum = (s_red[8]  + s_red[9])  + (s_red[10] + s_red[11])
                    + (s_red[12] + s_red[13]) + (s_red[14] + s_red[15]);

    // ---- Scatter (duplicate ids within a row possible -> atomicAdd) ----
    if (tid < S_ && valid) {
        atomicAdd(&rowo[id], e / sum);
    }
}

extern "C" void kernel_launch(void* const* d_in, const int* in_sizes, int n_in,
                              void* d_out, int out_size, void* d_ws, size_t ws_size,
                              hipStream_t stream) {
    const float* hs  = (const float*)d_in[0];
    const int*   ids = (const int*)d_in[1];
    const float* w   = (const float*)d_in[2];
    const float* bp  = (const float*)d_in[3];
    float*       out = (float*)d_out;

    rd90220_fused_v5<<<B_, NTHREADS_, 0, stream>>>(hs, ids, w, bp, out);
}